// Round 8
// baseline (244.429 us; speedup 1.0000x reference)
//
#include <hip/hip_runtime.h>

// Problem constants (fixed by setup_inputs)
constexpr int Bb = 4;
constexpr int Nn = 20000;
constexpr int Ff = 64;
constexpr int Hh = 128;
constexpr float BN_EPS = 1e-5f;
constexpr int NSLOTS = 64;               // BN-stat atomic spread (blockIdx & 63)
constexpr int NB = (Nn + 1023) / 1024;   // scan blocks (20)

typedef __attribute__((ext_vector_type(8))) short bf16x8;
typedef __attribute__((ext_vector_type(4))) float f32x4;

// bf16 helpers (RNE pack, cheap unpack)
__device__ inline unsigned f2bf(float f) {
    unsigned u = __float_as_uint(f);
    return (u + 0x7fffu + ((u >> 16) & 1u)) >> 16;
}
__device__ inline unsigned pack2(float lo, float hi) { return f2bf(lo) | (f2bf(hi) << 16); }
__device__ inline float bf_lo(unsigned w) { return __uint_as_float(w << 16); }
__device__ inline float bf_hi(unsigned w) { return __uint_as_float(w & 0xffff0000u); }

template <int NU>
__device__ inline void ldrow(unsigned* u, const unsigned* p) {
    if constexpr (NU == 2) { const uint2 t = *(const uint2*)p; u[0] = t.x; u[1] = t.y; }
    else { const uint4 t = *(const uint4*)p; u[0] = t.x; u[1] = t.y; u[2] = t.z; u[3] = t.w; }
}
template <int NU>
__device__ inline void acc_row(float* a, const unsigned* u, float nm) {
#pragma unroll
    for (int c = 0; c < NU; ++c) {
        a[2 * c]     = fmaf(nm, bf_lo(u[c]), a[2 * c]);
        a[2 * c + 1] = fmaf(nm, bf_hi(u[c]), a[2 * c + 1]);
    }
}

// ---------------------------------------------------------------------------
// K1: degree count over dst
__global__ void k_deg(const int* __restrict__ dst, int E, int* __restrict__ deg) {
    int e = blockIdx.x * blockDim.x + threadIdx.x;
    if (e < E) atomicAdd(&deg[dst[e]], 1);
}

// ---------------------------------------------------------------------------
// K2: multi-block scan over (deg+1). scan1: block-local excl -> rowptr, block
// totals -> bsum. scan2: exclusive-scan bsum (1 block). scan3: add offsets.
__global__ __launch_bounds__(1024) void k_scan1(const int* __restrict__ deg,
                                                int* __restrict__ rowptr,
                                                int* __restrict__ bsum) {
    __shared__ int wsum[16];
    const int tid = threadIdx.x, lane = tid & 63, wid = tid >> 6;
    const int i = blockIdx.x * 1024 + tid;
    const int cnt = (i < Nn) ? (deg[i] + 1) : 0;
    int v = cnt;
#pragma unroll
    for (int d = 1; d < 64; d <<= 1) {
        const int t = __shfl_up(v, d);
        if (lane >= d) v += t;
    }
    if (lane == 63) wsum[wid] = v;
    __syncthreads();
    if (wid == 0) {
        const int orig = (lane < 16) ? wsum[lane] : 0;
        int w = orig;
#pragma unroll
        for (int d = 1; d < 16; d <<= 1) {
            const int t = __shfl_up(w, d);
            if (lane >= d) w += t;
        }
        if (lane == 15) bsum[blockIdx.x] = w;
        if (lane < 16) wsum[lane] = w - orig;
    }
    __syncthreads();
    if (i < Nn) rowptr[i] = wsum[wid] + (v - cnt);   // block-local exclusive
}

__global__ void k_scan2(int* __restrict__ bsum) {
    const int lane = threadIdx.x;                    // 64 threads, 1 block
    const int v = (lane < NB) ? bsum[lane] : 0;
    int s = v;
#pragma unroll
    for (int d = 1; d < 64; d <<= 1) {
        const int t = __shfl_up(s, d);
        if (lane >= d) s += t;
    }
    if (lane < NB) bsum[lane] = s - v;               // exclusive
}

__global__ __launch_bounds__(1024) void k_scan3(const int* __restrict__ deg,
                                                int* __restrict__ rowptr,
                                                const int* __restrict__ bsum,
                                                int* __restrict__ cursor,
                                                float* __restrict__ dinv) {
    const int i = blockIdx.x * 1024 + threadIdx.x;
    if (i >= Nn) return;
    const int cnt = deg[i] + 1;
    const int excl = rowptr[i] + bsum[blockIdx.x];
    rowptr[i] = excl;
    cursor[i] = excl;
    dinv[i] = rsqrtf((float)cnt);
    if (i == Nn - 1) rowptr[Nn] = excl + cnt;
}

// ---------------------------------------------------------------------------
// K3: fill CSR + per-edge norm + per-node nsum (= sum of norms, for BN-fold)
__global__ void k_fill(const int* __restrict__ src, const int* __restrict__ dst, int E,
                       const float* __restrict__ dinv, int* __restrict__ cursor,
                       int* __restrict__ csr_src, float* __restrict__ csr_norm,
                       float* __restrict__ nsum) {
    int t = blockIdx.x * blockDim.x + threadIdx.x;
    int s, d;
    if (t < E) { s = src[t]; d = dst[t]; }
    else if (t < E + Nn) { s = d = t - E; }
    else return;
    int pos = atomicAdd(&cursor[d], 1);
    const float nm = dinv[s] * dinv[d];
    csr_src[pos]  = s;
    csr_norm[pos] = nm;
    atomicAdd(&nsum[d], nm);
}

// ---------------------------------------------------------------------------
// K4: convert x [B][N][64] fp32 -> xb [N][B][64] bf16 (node-major interleave)
__global__ void k_cvt(const float* __restrict__ x, unsigned* __restrict__ xb) {
    const int t = blockIdx.x * 256 + threadIdx.x;   // enumerates B*N*32 uint outputs
    if (t >= Bb * Nn * 32) return;
    const int c2 = t & 31;
    const int bn = t >> 5;
    const int n  = bn % Nn;
    const int b  = bn / Nn;
    const float2 v = *(const float2*)&x[(size_t)t * 2];
    xb[((size_t)n * Bb + b) * 32 + c2] = pack2(v.x, v.y);
}

// ---------------------------------------------------------------------------
// K5: weight prep (layer 1), FRAG-LINEAR: flat slot f -> {j=f&7, lane=(f>>3)&63,
// rest=f>>9: ks=rest&1, tt=rest>>1}; element = W[k][col], col=tt*16+(lane&15),
// k=ks*32+(lane>>4)*8+j. A wave's MFMA B-read is then 1KB contiguous.
__global__ void k_wt1(const float* __restrict__ W, unsigned short* __restrict__ WTf) {
    const int f = blockIdx.x * 256 + threadIdx.x;
    if (f >= 128 * Ff) return;
    const int j = f & 7, lane = (f >> 3) & 63, rest = f >> 9;
    const int ks = rest & 1, tt = rest >> 1;
    const int col = tt * 16 + (lane & 15);
    const int k = ks * 32 + ((lane >> 4) << 3) + j;
    WTf[f] = (unsigned short)f2bf(W[(size_t)k * 128 + col]);
}

// ---------------------------------------------------------------------------
// K6: fused BN1-finalize + WT2 fold (frag-linear) + shW2. Every block
// redundantly reduces 64-slot stats; blocks 0..63 write WT2f, block 64 shW2.
__global__ __launch_bounds__(128) void k_prep2(const float* __restrict__ gsum,
                                               const float* __restrict__ gsq,
                                               const float* __restrict__ gamma,
                                               const float* __restrict__ beta,
                                               const float* __restrict__ W2,
                                               unsigned short* __restrict__ WT2f,
                                               float* __restrict__ shW2) {
    __shared__ float sc_s[128], sh_s[128];
    const int c = threadIdx.x;
    float s = 0.f, q = 0.f;
    for (int j = 0; j < NSLOTS; ++j) { s += gsum[j * 128 + c]; q += gsq[j * 128 + c]; }
    const float inv = 1.0f / (float)(Bb * Nn);
    const float mu  = s * inv;
    const float var = q * inv - mu * mu;
    const float sc  = gamma[c] * rsqrtf(var + BN_EPS);
    sc_s[c] = sc;
    sh_s[c] = beta[c] - mu * sc;
    __syncthreads();
    if (blockIdx.x < 64) {
#pragma unroll
        for (int i = 0; i < 2; ++i) {
            const int f = blockIdx.x * 256 + i * 128 + c;
            const int j = f & 7, lane = (f >> 3) & 63, rest = f >> 9;  // 0..31
            const int ks = rest & 3, tt = rest >> 2;
            const int col = tt * 16 + (lane & 15);
            const int k = ks * 32 + ((lane >> 4) << 3) + j;
            WT2f[f] = (unsigned short)f2bf(sc_s[k] * W2[(size_t)k * 128 + col]);
        }
    } else {
        float a = 0.f;
        for (int k = 0; k < 128; ++k) a = fmaf(sh_s[k], W2[(size_t)k * 128 + c], a);
        shW2[c] = a;
    }
}

// ---------------------------------------------------------------------------
// K7: FUSED gather-aggregate + MFMA GEMM, high-occupancy version.
// 512 thr = 8 waves, block = 16 nodes = 64 rows. Wave w aggregates nodes
// blockIdx*16 + 2w + {0,1} into regs, packs bf16 into LDS sA. MFMA: wave w
// computes row-group (w&3)*16, col-half (w>>2)*64: acc[4] (16 VGPR). B-frags
// read DIRECTLY from frag-linear global WTf (L2 broadcast, 1KB/wave-read) --
// no sB in LDS. LDS ~18.5KB, __launch_bounds__(512,8) targets <=64 VGPR ->
// 32 waves/CU for the latency-bound gather (R7: 12 waves was the regression).
template <int K, bool L2E>
__global__ __launch_bounds__(512, 8) void k_fmm(const unsigned* __restrict__ G,
                                                const int* __restrict__ rowptr,
                                                const int* __restrict__ csr_src,
                                                const float* __restrict__ csr_norm,
                                                const unsigned short* __restrict__ WTf,
                                                const float* __restrict__ bias,
                                                const float* __restrict__ nsum,
                                                const float* __restrict__ shW2,
                                                unsigned short* __restrict__ Yout,
                                                float* __restrict__ gsum,
                                                float* __restrict__ gsq) {
    constexpr int NKS = K / 32;
    constexpr int AST = K + 8;
    constexpr int NU = K / 32;        // uints per lane per edge (2 or 4)
    constexpr int ROWU = Bb * K / 2;  // uints per node row (128 or 256)
    __shared__ alignas(16) unsigned short sA[64 * AST];
    __shared__ float lsum[128], lsq[128];

    const int tid = threadIdx.x;
    const int w = tid >> 6, lane = tid & 63;
    const int cg = lane & 15, kg = lane >> 4;
    const int row0 = blockIdx.x * 64;
    if (tid < 128) { lsum[tid] = 0.f; lsq[tid] = 0.f; }

    // fused aggregation: 2 nodes per wave
#pragma unroll
    for (int j = 0; j < 2; ++j) {
        const int nl = w * 2 + j;
        const int v = blockIdx.x * 16 + nl;
        const int beg = rowptr[v], end = rowptr[v + 1];
        float a[2 * NU];
#pragma unroll
        for (int c = 0; c < 2 * NU; ++c) a[c] = 0.f;
        int e = beg;
        for (; e + 2 <= end; e += 2) {
            const int s0 = csr_src[e], s1 = csr_src[e + 1];
            unsigned u0[NU], u1[NU];
            ldrow<NU>(u0, G + (size_t)s0 * ROWU + lane * NU);
            ldrow<NU>(u1, G + (size_t)s1 * ROWU + lane * NU);
            const float n0 = csr_norm[e], n1 = csr_norm[e + 1];
            acc_row<NU>(a, u0, n0);
            acc_row<NU>(a, u1, n1);
        }
        if (e < end) {
            unsigned u[NU];
            ldrow<NU>(u, G + (size_t)csr_src[e] * ROWU + lane * NU);
            acc_row<NU>(a, u, csr_norm[e]);
        }
        const int row = nl * 4 + kg;      // node-major row = node*4 + batch
        unsigned p[NU];
#pragma unroll
        for (int c = 0; c < NU; ++c) p[c] = pack2(a[2 * c], a[2 * c + 1]);
        if constexpr (NU == 2) *(uint2*)&sA[row * AST + cg * 4] = *(const uint2*)p;
        else                   *(uint4*)&sA[row * AST + cg * 8] = *(const uint4*)p;
    }
    __syncthreads();

    // MFMA: wave w -> rows (w&3)*16..+15, cols (w>>2)*64..+63
    const int rg = w & 3, ch = w >> 2;
    const int rowL = rg * 16 + cg;
    f32x4 acc[4];
#pragma unroll
    for (int t = 0; t < 4; ++t) acc[t] = (f32x4){0.f, 0.f, 0.f, 0.f};
#pragma unroll
    for (int ks = 0; ks < NKS; ++ks) {
        const bf16x8 av = *(const bf16x8*)&sA[rowL * AST + ks * 32 + kg * 8];
#pragma unroll
        for (int t = 0; t < 4; ++t) {
            const int tt = ch * 4 + t;
            const bf16x8 bv = *(const bf16x8*)&WTf[(size_t)((tt * NKS + ks) * 64 + lane) * 8];
            acc[t] = __builtin_amdgcn_mfma_f32_16x16x32_bf16(av, bv, acc[t], 0, 0, 0);
        }
    }

    // epilogue: +bias (+ns*shW2 for L2E), ReLU, bf16 store, BN partial stats
    const int rbase = rg * 16 + kg * 4;       // 4 regs = 4 batches of ONE node
    float ns = 0.f;
    if (L2E) ns = nsum[(row0 + rbase) >> 2];
#pragma unroll
    for (int t = 0; t < 4; ++t) {
        const int col = (ch * 4 + t) * 16 + cg;
        float badd = bias[col];
        if (L2E) badd = fmaf(ns, shW2[col], badd);
        float s = 0.f, q = 0.f;
#pragma unroll
        for (int jj = 0; jj < 4; ++jj) {
            const float y = fmaxf(acc[t][jj] + badd, 0.f);
            Yout[(size_t)(row0 + rbase + jj) * 128 + col] = (unsigned short)f2bf(y);
            s += y; q = fmaf(y, y, q);
        }
        atomicAdd(&lsum[col], s);
        atomicAdd(&lsq[col], q);
    }
    __syncthreads();
    float* gs = gsum + (size_t)(blockIdx.x & (NSLOTS - 1)) * 128;
    float* gq = gsq  + (size_t)(blockIdx.x & (NSLOTS - 1)) * 128;
    if (tid < 128) { atomicAdd(&gs[tid], lsum[tid]); atomicAdd(&gq[tid], lsq[tid]); }
}

// ---------------------------------------------------------------------------
// K8: BN2 finalize folded into classifier weights:
//   wcs[c] = sc2[c]*Wc[c],  kc = sum_c sh2[c]*Wc[c] + bc
__global__ void k_bnfin2(const float* __restrict__ gsum, const float* __restrict__ gsq,
                         const float* __restrict__ gamma, const float* __restrict__ beta,
                         const float* __restrict__ Wc, const float* __restrict__ bc,
                         float* __restrict__ wcs, float* __restrict__ kc) {
    __shared__ float red[128];
    const int c = threadIdx.x;
    float s = 0.f, q = 0.f;
    for (int j = 0; j < NSLOTS; ++j) { s += gsum[j * 128 + c]; q += gsq[j * 128 + c]; }
    const float inv = 1.0f / (float)(Bb * Nn);
    const float mu  = s * inv;
    const float var = q * inv - mu * mu;
    const float sc  = gamma[c] * rsqrtf(var + BN_EPS);
    const float sh  = beta[c] - mu * sc;
    const float w   = Wc[c];
    wcs[c] = sc * w;
    red[c] = sh * w;
    __syncthreads();
    for (int st = 64; st; st >>= 1) {
        if (c < st) red[c] += red[c + st];
        __syncthreads();
    }
    if (c == 0) kc[0] = red[0] + bc[0];
}

// ---------------------------------------------------------------------------
// K9: classifier on bf16 h2: out[b*Nn+n] = sum_c h2[r][c]*wcs[c] + kc
__global__ __launch_bounds__(256) void k_cls(const unsigned* __restrict__ h2,
                                             const float* __restrict__ wcs,
                                             const float* __restrict__ kc,
                                             float* __restrict__ out) {
    const int wave = threadIdx.x >> 6;
    const int lane = threadIdx.x & 63;
    const size_t row = (size_t)blockIdx.x * 4 + wave;
    if (row >= (size_t)Bb * Nn) return;
    const unsigned w = h2[row * 64 + lane];          // 2 channels
    const float2 wc = *(const float2*)&wcs[lane * 2];
    float p = bf_lo(w) * wc.x + bf_hi(w) * wc.y;
#pragma unroll
    for (int off = 32; off; off >>= 1) p += __shfl_down(p, off);
    if (lane == 0) {
        const int n = (int)(row >> 2), b = (int)(row & 3);
        out[(size_t)b * Nn + n] = p + kc[0];
    }
}

// ---------------------------------------------------------------------------
extern "C" void kernel_launch(void* const* d_in, const int* in_sizes, int n_in,
                              void* d_out, int out_size, void* d_ws, size_t ws_size,
                              hipStream_t stream) {
    const float* x      = (const float*)d_in[0];
    const int*   ei     = (const int*)d_in[1];
    const float* W1     = (const float*)d_in[2];
    const float* b1     = (const float*)d_in[3];
    const float* W2     = (const float*)d_in[4];
    const float* b2     = (const float*)d_in[5];
    const float* gamma1 = (const float*)d_in[6];
    const float* beta1  = (const float*)d_in[7];
    const float* gamma2 = (const float*)d_in[8];
    const float* beta2  = (const float*)d_in[9];
    const float* Wc     = (const float*)d_in[10];
    const float* bc     = (const float*)d_in[11];
    float* out = (float*)d_out;

    const int E = in_sizes[1] / 2;
    const int* src = ei;
    const int* dst = ei + E;

    char* ws = (char*)d_ws;
    size_t off = 0;
    auto alloc = [&](size_t bytes) -> char* {
        char* p = ws + off;
        off += (bytes + 255) & ~(size_t)255;
        return p;
    };
    // zero-init region: deg, nsum, gstat contiguous -> ONE memset
    int*      deg      = (int*)     alloc((size_t)Nn * 4);
    float*    nsum     = (float*)   alloc((size_t)Nn * 4);
    float*    gstat    = (float*)   alloc((size_t)4 * NSLOTS * 128 * 4);
    const size_t zspan = (size_t)((char*)(gstat + 4 * NSLOTS * 128) - (char*)deg);
    float* gsum1 = gstat;
    float* gsq1  = gstat + NSLOTS * 128;
    float* gsum2 = gstat + 2 * NSLOTS * 128;
    float* gsq2  = gstat + 3 * NSLOTS * 128;

    int*      cursor   = (int*)     alloc((size_t)Nn * 4);
    int*      rowptr   = (int*)     alloc((size_t)(Nn + 1) * 4);
    int*      bsum     = (int*)     alloc((size_t)NB * 4);
    float*    dinv     = (float*)   alloc((size_t)Nn * 4);
    int*      csr_src  = (int*)     alloc((size_t)(E + Nn) * 4);
    float*    csr_norm = (float*)   alloc((size_t)(E + Nn) * 4);
    float*    wcs      = (float*)   alloc(128 * 4);
    float*    kc       = (float*)   alloc(256);
    unsigned short* WT1f = (unsigned short*)alloc((size_t)128 * Ff * 2);
    unsigned short* WT2f = (unsigned short*)alloc((size_t)128 * Hh * 2);
    float*          shW2 = (float*)         alloc((size_t)128 * 4);
    unsigned*       xb   = (unsigned*)      alloc((size_t)Nn * Bb * 32 * 4);  // bf16 x node-major
    unsigned short* h1b  = (unsigned short*)alloc((size_t)Bb * Nn * Hh * 2);  // bf16 [80000][128]
    unsigned short* h2b  = (unsigned short*)alloc((size_t)Bb * Nn * Hh * 2);  // bf16 [80000][128]

    (void)hipMemsetAsync(deg, 0, zspan, stream);

    k_deg<<<(E + 255) / 256, 256, 0, stream>>>(dst, E, deg);
    k_scan1<<<NB, 1024, 0, stream>>>(deg, rowptr, bsum);
    k_scan2<<<1, 64, 0, stream>>>(bsum);
    k_scan3<<<NB, 1024, 0, stream>>>(deg, rowptr, bsum, cursor, dinv);
    k_fill<<<(E + Nn + 255) / 256, 256, 0, stream>>>(src, dst, E, dinv, cursor,
                                                     csr_src, csr_norm, nsum);
    k_cvt<<<(Bb * Nn * 32 + 255) / 256, 256, 0, stream>>>(x, xb);
    k_wt1<<<(128 * Ff) / 256, 256, 0, stream>>>(W1, WT1f);

    // Layer 1: fused agg(x)@W1 (+b1, ReLU, BN1 stats, bf16 out)
    k_fmm<Ff, false><<<Nn / 16, 512, 0, stream>>>(
        xb, rowptr, csr_src, csr_norm, WT1f, b1, nullptr, nullptr, h1b, gsum1, gsq1);
    // BN1 finalize + fold into WT2f/shW2
    k_prep2<<<65, 128, 0, stream>>>(gsum1, gsq1, gamma1, beta1, W2, WT2f, shW2);
    // Layer 2: fused agg(h1)@(sc1.W2) + nsum*(sh1@W2) + b2, ReLU, BN2 stats
    k_fmm<Hh, true><<<Nn / 16, 512, 0, stream>>>(
        (const unsigned*)h1b, rowptr, csr_src, csr_norm, WT2f, b2, nsum, shW2,
        h2b, gsum2, gsq2);
    k_bnfin2<<<1, Hh, 0, stream>>>(gsum2, gsq2, gamma2, beta2, Wc, bc, wcs, kc);

    // Classifier (BN2 folded into wcs/kc)
    k_cls<<<(Bb * Nn + 3) / 4, 256, 0, stream>>>((const unsigned*)h2b, wcs, kc, out);
}

// Round 9
// 223.008 us; speedup vs baseline: 1.0961x; 1.0961x over previous
//
#include <hip/hip_runtime.h>

// Problem constants (fixed by setup_inputs)
constexpr int Bb = 4;
constexpr int Nn = 20000;
constexpr int Ff = 64;
constexpr int Hh = 128;
constexpr float BN_EPS = 1e-5f;
constexpr int NSLOTS = 64;               // BN-stat atomic spread (blockIdx & 63)
constexpr int NB = (Nn + 1023) / 1024;   // scan blocks (20)

typedef __attribute__((ext_vector_type(8))) short bf16x8;
typedef __attribute__((ext_vector_type(4))) float f32x4;

// bf16 helpers (RNE pack, cheap unpack)
__device__ inline unsigned f2bf(float f) {
    unsigned u = __float_as_uint(f);
    return (u + 0x7fffu + ((u >> 16) & 1u)) >> 16;
}
__device__ inline unsigned pack2(float lo, float hi) { return f2bf(lo) | (f2bf(hi) << 16); }
__device__ inline float bf_lo(unsigned w) { return __uint_as_float(w << 16); }
__device__ inline float bf_hi(unsigned w) { return __uint_as_float(w & 0xffff0000u); }

template <int NU>
__device__ inline void ldrow(unsigned* u, const unsigned* p) {
    if constexpr (NU == 2) { const uint2 t = *(const uint2*)p; u[0] = t.x; u[1] = t.y; }
    else { const uint4 t = *(const uint4*)p; u[0] = t.x; u[1] = t.y; u[2] = t.z; u[3] = t.w; }
}
template <int NU>
__device__ inline void acc_row(float* a, const unsigned* u, float nm) {
#pragma unroll
    for (int c = 0; c < NU; ++c) {
        a[2 * c]     = fmaf(nm, bf_lo(u[c]), a[2 * c]);
        a[2 * c + 1] = fmaf(nm, bf_hi(u[c]), a[2 * c + 1]);
    }
}

// ---------------------------------------------------------------------------
// K1: degree count over dst
__global__ void k_deg(const int* __restrict__ dst, int E, int* __restrict__ deg) {
    int e = blockIdx.x * blockDim.x + threadIdx.x;
    if (e < E) atomicAdd(&deg[dst[e]], 1);
}

// ---------------------------------------------------------------------------
// K2: multi-block scan over (deg+1). scan1: block-local excl -> rowptr, block
// totals -> bsum. scan2: exclusive-scan bsum (1 block). scan3: add offsets.
__global__ __launch_bounds__(1024) void k_scan1(const int* __restrict__ deg,
                                                int* __restrict__ rowptr,
                                                int* __restrict__ bsum) {
    __shared__ int wsum[16];
    const int tid = threadIdx.x, lane = tid & 63, wid = tid >> 6;
    const int i = blockIdx.x * 1024 + tid;
    const int cnt = (i < Nn) ? (deg[i] + 1) : 0;
    int v = cnt;
#pragma unroll
    for (int d = 1; d < 64; d <<= 1) {
        const int t = __shfl_up(v, d);
        if (lane >= d) v += t;
    }
    if (lane == 63) wsum[wid] = v;
    __syncthreads();
    if (wid == 0) {
        const int orig = (lane < 16) ? wsum[lane] : 0;
        int w = orig;
#pragma unroll
        for (int d = 1; d < 16; d <<= 1) {
            const int t = __shfl_up(w, d);
            if (lane >= d) w += t;
        }
        if (lane == 15) bsum[blockIdx.x] = w;
        if (lane < 16) wsum[lane] = w - orig;
    }
    __syncthreads();
    if (i < Nn) rowptr[i] = wsum[wid] + (v - cnt);   // block-local exclusive
}

__global__ void k_scan2(int* __restrict__ bsum) {
    const int lane = threadIdx.x;                    // 64 threads, 1 block
    const int v = (lane < NB) ? bsum[lane] : 0;
    int s = v;
#pragma unroll
    for (int d = 1; d < 64; d <<= 1) {
        const int t = __shfl_up(s, d);
        if (lane >= d) s += t;
    }
    if (lane < NB) bsum[lane] = s - v;               // exclusive
}

__global__ __launch_bounds__(1024) void k_scan3(const int* __restrict__ deg,
                                                int* __restrict__ rowptr,
                                                const int* __restrict__ bsum,
                                                int* __restrict__ cursor,
                                                float* __restrict__ dinv) {
    const int i = blockIdx.x * 1024 + threadIdx.x;
    if (i >= Nn) return;
    const int cnt = deg[i] + 1;
    const int excl = rowptr[i] + bsum[blockIdx.x];
    rowptr[i] = excl;
    cursor[i] = excl;
    dinv[i] = rsqrtf((float)cnt);
    if (i == Nn - 1) rowptr[Nn] = excl + cnt;
}

// ---------------------------------------------------------------------------
// K3: fill CSR + per-edge norm + per-node nsum (= sum of norms, for BN-fold)
__global__ void k_fill(const int* __restrict__ src, const int* __restrict__ dst, int E,
                       const float* __restrict__ dinv, int* __restrict__ cursor,
                       int* __restrict__ csr_src, float* __restrict__ csr_norm,
                       float* __restrict__ nsum) {
    int t = blockIdx.x * blockDim.x + threadIdx.x;
    int s, d;
    if (t < E) { s = src[t]; d = dst[t]; }
    else if (t < E + Nn) { s = d = t - E; }
    else return;
    int pos = atomicAdd(&cursor[d], 1);
    const float nm = dinv[s] * dinv[d];
    csr_src[pos]  = s;
    csr_norm[pos] = nm;
    atomicAdd(&nsum[d], nm);
}

// ---------------------------------------------------------------------------
// K4: convert x [B][N][64] fp32 -> xb [N][B][64] bf16 (node-major interleave)
__global__ void k_cvt(const float* __restrict__ x, unsigned* __restrict__ xb) {
    const int t = blockIdx.x * 256 + threadIdx.x;   // enumerates B*N*32 uint outputs
    if (t >= Bb * Nn * 32) return;
    const int c2 = t & 31;
    const int bn = t >> 5;
    const int n  = bn % Nn;
    const int b  = bn / Nn;
    const float2 v = *(const float2*)&x[(size_t)t * 2];
    xb[((size_t)n * Bb + b) * 32 + c2] = pack2(v.x, v.y);
}

// ---------------------------------------------------------------------------
// K5: weight prep (layer 1), FRAG-LINEAR: flat slot f -> {j=f&7, lane=(f>>3)&63,
// rest=f>>9: ks=rest&1, tt=rest>>1}; element = W[k][col], col=tt*16+(lane&15),
// k=ks*32+(lane>>4)*8+j. A wave's MFMA B-read is then 1KB contiguous.
__global__ void k_wt1(const float* __restrict__ W, unsigned short* __restrict__ WTf) {
    const int f = blockIdx.x * 256 + threadIdx.x;
    if (f >= 128 * Ff) return;
    const int j = f & 7, lane = (f >> 3) & 63, rest = f >> 9;
    const int ks = rest & 1, tt = rest >> 1;
    const int col = tt * 16 + (lane & 15);
    const int k = ks * 32 + ((lane >> 4) << 3) + j;
    WTf[f] = (unsigned short)f2bf(W[(size_t)k * 128 + col]);
}

// ---------------------------------------------------------------------------
// K6: fused BN1-finalize + WT2 fold (frag-linear) + shW2. Every block
// redundantly reduces 64-slot stats; blocks 0..63 write WT2f, block 64 shW2.
__global__ __launch_bounds__(128) void k_prep2(const float* __restrict__ gsum,
                                               const float* __restrict__ gsq,
                                               const float* __restrict__ gamma,
                                               const float* __restrict__ beta,
                                               const float* __restrict__ W2,
                                               unsigned short* __restrict__ WT2f,
                                               float* __restrict__ shW2) {
    __shared__ float sc_s[128], sh_s[128];
    const int c = threadIdx.x;
    float s = 0.f, q = 0.f;
    for (int j = 0; j < NSLOTS; ++j) { s += gsum[j * 128 + c]; q += gsq[j * 128 + c]; }
    const float inv = 1.0f / (float)(Bb * Nn);
    const float mu  = s * inv;
    const float var = q * inv - mu * mu;
    const float sc  = gamma[c] * rsqrtf(var + BN_EPS);
    sc_s[c] = sc;
    sh_s[c] = beta[c] - mu * sc;
    __syncthreads();
    if (blockIdx.x < 64) {
#pragma unroll
        for (int i = 0; i < 2; ++i) {
            const int f = blockIdx.x * 256 + i * 128 + c;
            const int j = f & 7, lane = (f >> 3) & 63, rest = f >> 9;  // 0..31
            const int ks = rest & 3, tt = rest >> 2;
            const int col = tt * 16 + (lane & 15);
            const int k = ks * 32 + ((lane >> 4) << 3) + j;
            WT2f[f] = (unsigned short)f2bf(sc_s[k] * W2[(size_t)k * 128 + col]);
        }
    } else {
        float a = 0.f;
        for (int k = 0; k < 128; ++k) a = fmaf(sh_s[k], W2[(size_t)k * 128 + c], a);
        shW2[c] = a;
    }
}

// ---------------------------------------------------------------------------
// K7: FUSED gather-aggregate + MFMA GEMM, wave-independent version.
// 256 thr = 4 waves; wave w owns nodes blockIdx*16+w*4..+3 = sA rows w*16..+15
// END-TO-END: gather (unroll x8 -> 8 outstanding 1KB loads/wave), pack to its
// own sA rows, MFMA its own rows (B-frags direct from frag-linear global WTf),
// epilogue. NO mid-block barrier (R8's barrier gated MFMA on slowest gather;
// R8's unroll x2 halved per-wave MLP -- BW tracks waves x outstanding loads).
template <int K, bool L2E>
__global__ __launch_bounds__(256, 4) void k_fmm(const unsigned* __restrict__ G,
                                                const int* __restrict__ rowptr,
                                                const int* __restrict__ csr_src,
                                                const float* __restrict__ csr_norm,
                                                const unsigned short* __restrict__ WTf,
                                                const float* __restrict__ bias,
                                                const float* __restrict__ nsum,
                                                const float* __restrict__ shW2,
                                                unsigned short* __restrict__ Yout,
                                                float* __restrict__ gsum,
                                                float* __restrict__ gsq) {
    constexpr int NKS = K / 32;
    constexpr int AST = K + 8;
    constexpr int NU = K / 32;        // uints per lane per edge (2 or 4)
    constexpr int ROWU = Bb * K / 2;  // uints per node row (128 or 256)
    __shared__ alignas(16) unsigned short sA[64 * AST];
    __shared__ float lsum[128], lsq[128];

    const int tid = threadIdx.x;
    const int w = tid >> 6, lane = tid & 63;
    const int cg = lane & 15, kg = lane >> 4;
    const int row0 = blockIdx.x * 64;
    if (tid < 128) { lsum[tid] = 0.f; lsq[tid] = 0.f; }
    __syncthreads();   // protect lsum init (all waves at start: no imbalance)

    // gather 4 nodes into own sA rows (no cross-wave dependency)
#pragma unroll
    for (int j = 0; j < 4; ++j) {
        const int nl = w * 4 + j;
        const int v = blockIdx.x * 16 + nl;
        const int beg = rowptr[v], end = rowptr[v + 1];
        float a[2 * NU];
#pragma unroll
        for (int c = 0; c < 2 * NU; ++c) a[c] = 0.f;
        int e = beg;
        for (; e + 8 <= end; e += 8) {     // 8 outstanding 1KB gathers
            unsigned u[8][NU];
            int si[8];
#pragma unroll
            for (int q = 0; q < 8; ++q) si[q] = csr_src[e + q];
#pragma unroll
            for (int q = 0; q < 8; ++q)
                ldrow<NU>(u[q], G + (size_t)si[q] * ROWU + lane * NU);
#pragma unroll
            for (int q = 0; q < 8; ++q) acc_row<NU>(a, u[q], csr_norm[e + q]);
        }
        for (; e + 4 <= end; e += 4) {
            unsigned u[4][NU];
            int si[4];
#pragma unroll
            for (int q = 0; q < 4; ++q) si[q] = csr_src[e + q];
#pragma unroll
            for (int q = 0; q < 4; ++q)
                ldrow<NU>(u[q], G + (size_t)si[q] * ROWU + lane * NU);
#pragma unroll
            for (int q = 0; q < 4; ++q) acc_row<NU>(a, u[q], csr_norm[e + q]);
        }
        for (; e < end; ++e) {
            unsigned u[NU];
            ldrow<NU>(u, G + (size_t)csr_src[e] * ROWU + lane * NU);
            acc_row<NU>(a, u, csr_norm[e]);
        }
        const int row = nl * 4 + kg;      // node-major row = node*4 + batch
        unsigned p[NU];
#pragma unroll
        for (int c = 0; c < NU; ++c) p[c] = pack2(a[2 * c], a[2 * c + 1]);
        if constexpr (NU == 2) *(uint2*)&sA[row * AST + cg * 4] = *(const uint2*)p;
        else                   *(uint4*)&sA[row * AST + cg * 8] = *(const uint4*)p;
    }
    // NO barrier: wave w MFMAs exactly the rows it wrote (same-wave LDS RAW
    // ordering is handled by compiler lgkmcnt waits).

    // MFMA: wave w -> rows w*16..+15, all 128 cols; B direct from global WTf
    const int rowL = w * 16 + cg;
    f32x4 acc[8];
#pragma unroll
    for (int t = 0; t < 8; ++t) acc[t] = (f32x4){0.f, 0.f, 0.f, 0.f};
#pragma unroll
    for (int ks = 0; ks < NKS; ++ks) {
        const bf16x8 av = *(const bf16x8*)&sA[rowL * AST + ks * 32 + kg * 8];
#pragma unroll
        for (int t = 0; t < 8; ++t) {
            const bf16x8 bv = *(const bf16x8*)&WTf[(size_t)((t * NKS + ks) * 64 + lane) * 8];
            acc[t] = __builtin_amdgcn_mfma_f32_16x16x32_bf16(av, bv, acc[t], 0, 0, 0);
        }
    }

    // epilogue: +bias (+ns*shW2 for L2E), ReLU, bf16 store, BN partial stats
    const int rbase = w * 16 + kg * 4;        // 4 regs = 4 batches of ONE node
    float ns = 0.f;
    if (L2E) ns = nsum[(row0 + rbase) >> 2];
#pragma unroll
    for (int t = 0; t < 8; ++t) {
        const int col = t * 16 + cg;
        float badd = bias[col];
        if (L2E) badd = fmaf(ns, shW2[col], badd);
        float s = 0.f, q = 0.f;
#pragma unroll
        for (int jj = 0; jj < 4; ++jj) {
            const float y = fmaxf(acc[t][jj] + badd, 0.f);
            Yout[(size_t)(row0 + rbase + jj) * 128 + col] = (unsigned short)f2bf(y);
            s += y; q = fmaf(y, y, q);
        }
        atomicAdd(&lsum[col], s);
        atomicAdd(&lsq[col], q);
    }
    __syncthreads();   // pre-flush (tiny: only delays the 128 flush lanes)
    float* gs = gsum + (size_t)(blockIdx.x & (NSLOTS - 1)) * 128;
    float* gq = gsq  + (size_t)(blockIdx.x & (NSLOTS - 1)) * 128;
    if (tid < 128) { atomicAdd(&gs[tid], lsum[tid]); atomicAdd(&gq[tid], lsq[tid]); }
}

// ---------------------------------------------------------------------------
// K8: BN2 finalize folded into classifier weights:
//   wcs[c] = sc2[c]*Wc[c],  kc = sum_c sh2[c]*Wc[c] + bc
__global__ void k_bnfin2(const float* __restrict__ gsum, const float* __restrict__ gsq,
                         const float* __restrict__ gamma, const float* __restrict__ beta,
                         const float* __restrict__ Wc, const float* __restrict__ bc,
                         float* __restrict__ wcs, float* __restrict__ kc) {
    __shared__ float red[128];
    const int c = threadIdx.x;
    float s = 0.f, q = 0.f;
    for (int j = 0; j < NSLOTS; ++j) { s += gsum[j * 128 + c]; q += gsq[j * 128 + c]; }
    const float inv = 1.0f / (float)(Bb * Nn);
    const float mu  = s * inv;
    const float var = q * inv - mu * mu;
    const float sc  = gamma[c] * rsqrtf(var + BN_EPS);
    const float sh  = beta[c] - mu * sc;
    const float w   = Wc[c];
    wcs[c] = sc * w;
    red[c] = sh * w;
    __syncthreads();
    for (int st = 64; st; st >>= 1) {
        if (c < st) red[c] += red[c + st];
        __syncthreads();
    }
    if (c == 0) kc[0] = red[0] + bc[0];
}

// ---------------------------------------------------------------------------
// K9: classifier on bf16 h2: out[b*Nn+n] = sum_c h2[r][c]*wcs[c] + kc
__global__ __launch_bounds__(256) void k_cls(const unsigned* __restrict__ h2,
                                             const float* __restrict__ wcs,
                                             const float* __restrict__ kc,
                                             float* __restrict__ out) {
    const int wave = threadIdx.x >> 6;
    const int lane = threadIdx.x & 63;
    const size_t row = (size_t)blockIdx.x * 4 + wave;
    if (row >= (size_t)Bb * Nn) return;
    const unsigned w = h2[row * 64 + lane];          // 2 channels
    const float2 wc = *(const float2*)&wcs[lane * 2];
    float p = bf_lo(w) * wc.x + bf_hi(w) * wc.y;
#pragma unroll
    for (int off = 32; off; off >>= 1) p += __shfl_down(p, off);
    if (lane == 0) {
        const int n = (int)(row >> 2), b = (int)(row & 3);
        out[(size_t)b * Nn + n] = p + kc[0];
    }
}

// ---------------------------------------------------------------------------
extern "C" void kernel_launch(void* const* d_in, const int* in_sizes, int n_in,
                              void* d_out, int out_size, void* d_ws, size_t ws_size,
                              hipStream_t stream) {
    const float* x      = (const float*)d_in[0];
    const int*   ei     = (const int*)d_in[1];
    const float* W1     = (const float*)d_in[2];
    const float* b1     = (const float*)d_in[3];
    const float* W2     = (const float*)d_in[4];
    const float* b2     = (const float*)d_in[5];
    const float* gamma1 = (const float*)d_in[6];
    const float* beta1  = (const float*)d_in[7];
    const float* gamma2 = (const float*)d_in[8];
    const float* beta2  = (const float*)d_in[9];
    const float* Wc     = (const float*)d_in[10];
    const float* bc     = (const float*)d_in[11];
    float* out = (float*)d_out;

    const int E = in_sizes[1] / 2;
    const int* src = ei;
    const int* dst = ei + E;

    char* ws = (char*)d_ws;
    size_t off = 0;
    auto alloc = [&](size_t bytes) -> char* {
        char* p = ws + off;
        off += (bytes + 255) & ~(size_t)255;
        return p;
    };
    // zero-init region: deg, nsum, gstat contiguous -> ONE memset
    int*      deg      = (int*)     alloc((size_t)Nn * 4);
    float*    nsum     = (float*)   alloc((size_t)Nn * 4);
    float*    gstat    = (float*)   alloc((size_t)4 * NSLOTS * 128 * 4);
    const size_t zspan = (size_t)((char*)(gstat + 4 * NSLOTS * 128) - (char*)deg);
    float* gsum1 = gstat;
    float* gsq1  = gstat + NSLOTS * 128;
    float* gsum2 = gstat + 2 * NSLOTS * 128;
    float* gsq2  = gstat + 3 * NSLOTS * 128;

    int*      cursor   = (int*)     alloc((size_t)Nn * 4);
    int*      rowptr   = (int*)     alloc((size_t)(Nn + 1) * 4);
    int*      bsum     = (int*)     alloc((size_t)NB * 4);
    float*    dinv     = (float*)   alloc((size_t)Nn * 4);
    int*      csr_src  = (int*)     alloc((size_t)(E + Nn) * 4);
    float*    csr_norm = (float*)   alloc((size_t)(E + Nn) * 4);
    float*    wcs      = (float*)   alloc(128 * 4);
    float*    kc       = (float*)   alloc(256);
    unsigned short* WT1f = (unsigned short*)alloc((size_t)128 * Ff * 2);
    unsigned short* WT2f = (unsigned short*)alloc((size_t)128 * Hh * 2);
    float*          shW2 = (float*)         alloc((size_t)128 * 4);
    unsigned*       xb   = (unsigned*)      alloc((size_t)Nn * Bb * 32 * 4);  // bf16 x node-major
    unsigned short* h1b  = (unsigned short*)alloc((size_t)Bb * Nn * Hh * 2);  // bf16 [80000][128]
    unsigned short* h2b  = (unsigned short*)alloc((size_t)Bb * Nn * Hh * 2);  // bf16 [80000][128]

    (void)hipMemsetAsync(deg, 0, zspan, stream);

    k_deg<<<(E + 255) / 256, 256, 0, stream>>>(dst, E, deg);
    k_scan1<<<NB, 1024, 0, stream>>>(deg, rowptr, bsum);
    k_scan2<<<1, 64, 0, stream>>>(bsum);
    k_scan3<<<NB, 1024, 0, stream>>>(deg, rowptr, bsum, cursor, dinv);
    k_fill<<<(E + Nn + 255) / 256, 256, 0, stream>>>(src, dst, E, dinv, cursor,
                                                     csr_src, csr_norm, nsum);
    k_cvt<<<(Bb * Nn * 32 + 255) / 256, 256, 0, stream>>>(x, xb);
    k_wt1<<<(128 * Ff) / 256, 256, 0, stream>>>(W1, WT1f);

    // Layer 1: fused agg(x)@W1 (+b1, ReLU, BN1 stats, bf16 out)
    k_fmm<Ff, false><<<Nn / 16, 256, 0, stream>>>(
        xb, rowptr, csr_src, csr_norm, WT1f, b1, nullptr, nullptr, h1b, gsum1, gsq1);
    // BN1 finalize + fold into WT2f/shW2
    k_prep2<<<65, 128, 0, stream>>>(gsum1, gsq1, gamma1, beta1, W2, WT2f, shW2);
    // Layer 2: fused agg(h1)@(sc1.W2) + nsum*(sh1@W2) + b2, ReLU, BN2 stats
    k_fmm<Hh, true><<<Nn / 16, 256, 0, stream>>>(
        (const unsigned*)h1b, rowptr, csr_src, csr_norm, WT2f, b2, nsum, shW2,
        h2b, gsum2, gsq2);
    k_bnfin2<<<1, Hh, 0, stream>>>(gsum2, gsq2, gamma2, beta2, Wc, bc, wcs, kc);

    // Classifier (BN2 folded into wcs/kc)
    k_cls<<<(Bb * Nn + 3) / 4, 256, 0, stream>>>((const unsigned*)h2b, wcs, kc, out);
}

// Round 10
// 184.250 us; speedup vs baseline: 1.3266x; 1.2104x over previous
//
#include <hip/hip_runtime.h>

// Problem constants (fixed by setup_inputs)
constexpr int Bb = 4;
constexpr int Nn = 20000;
constexpr int Ff = 64;
constexpr int Hh = 128;
constexpr float BN_EPS = 1e-5f;
constexpr int NSLOTS = 64;               // BN-stat atomic spread (blockIdx & 63)
constexpr int NB = (Nn + 1023) / 1024;   // scan blocks (20)

typedef __attribute__((ext_vector_type(8))) short bf16x8;
typedef __attribute__((ext_vector_type(4))) float f32x4;

// bf16 helpers (RNE pack, cheap unpack)
__device__ inline unsigned f2bf(float f) {
    unsigned u = __float_as_uint(f);
    return (u + 0x7fffu + ((u >> 16) & 1u)) >> 16;
}
__device__ inline unsigned pack2(float lo, float hi) { return f2bf(lo) | (f2bf(hi) << 16); }
__device__ inline float bf_lo(unsigned w) { return __uint_as_float(w << 16); }
__device__ inline float bf_hi(unsigned w) { return __uint_as_float(w & 0xffff0000u); }

template <int NU>
__device__ inline void ldrow(unsigned* u, const unsigned* p) {
    if constexpr (NU == 2) { const uint2 t = *(const uint2*)p; u[0] = t.x; u[1] = t.y; }
    else { const uint4 t = *(const uint4*)p; u[0] = t.x; u[1] = t.y; u[2] = t.z; u[3] = t.w; }
}
template <int NU>
__device__ inline void acc_row(float* a, const unsigned* u, float nm) {
#pragma unroll
    for (int c = 0; c < NU; ++c) {
        a[2 * c]     = fmaf(nm, bf_lo(u[c]), a[2 * c]);
        a[2 * c + 1] = fmaf(nm, bf_hi(u[c]), a[2 * c + 1]);
    }
}

// ---------------------------------------------------------------------------
// K1: degree count over dst
__global__ void k_deg(const int* __restrict__ dst, int E, int* __restrict__ deg) {
    int e = blockIdx.x * blockDim.x + threadIdx.x;
    if (e < E) atomicAdd(&deg[dst[e]], 1);
}

// ---------------------------------------------------------------------------
// K2: multi-block scan over (deg+1). scan1: block-local excl -> rowptr, block
// totals -> bsum. scan2: exclusive-scan bsum (1 block). scan3: add offsets.
__global__ __launch_bounds__(1024) void k_scan1(const int* __restrict__ deg,
                                                int* __restrict__ rowptr,
                                                int* __restrict__ bsum) {
    __shared__ int wsum[16];
    const int tid = threadIdx.x, lane = tid & 63, wid = tid >> 6;
    const int i = blockIdx.x * 1024 + tid;
    const int cnt = (i < Nn) ? (deg[i] + 1) : 0;
    int v = cnt;
#pragma unroll
    for (int d = 1; d < 64; d <<= 1) {
        const int t = __shfl_up(v, d);
        if (lane >= d) v += t;
    }
    if (lane == 63) wsum[wid] = v;
    __syncthreads();
    if (wid == 0) {
        const int orig = (lane < 16) ? wsum[lane] : 0;
        int w = orig;
#pragma unroll
        for (int d = 1; d < 16; d <<= 1) {
            const int t = __shfl_up(w, d);
            if (lane >= d) w += t;
        }
        if (lane == 15) bsum[blockIdx.x] = w;
        if (lane < 16) wsum[lane] = w - orig;
    }
    __syncthreads();
    if (i < Nn) rowptr[i] = wsum[wid] + (v - cnt);   // block-local exclusive
}

__global__ void k_scan2(int* __restrict__ bsum) {
    const int lane = threadIdx.x;                    // 64 threads, 1 block
    const int v = (lane < NB) ? bsum[lane] : 0;
    int s = v;
#pragma unroll
    for (int d = 1; d < 64; d <<= 1) {
        const int t = __shfl_up(s, d);
        if (lane >= d) s += t;
    }
    if (lane < NB) bsum[lane] = s - v;               // exclusive
}

__global__ __launch_bounds__(1024) void k_scan3(const int* __restrict__ deg,
                                                int* __restrict__ rowptr,
                                                const int* __restrict__ bsum,
                                                int* __restrict__ cursor,
                                                float* __restrict__ dinv) {
    const int i = blockIdx.x * 1024 + threadIdx.x;
    if (i >= Nn) return;
    const int cnt = deg[i] + 1;
    const int excl = rowptr[i] + bsum[blockIdx.x];
    rowptr[i] = excl;
    cursor[i] = excl;
    dinv[i] = rsqrtf((float)cnt);
    if (i == Nn - 1) rowptr[Nn] = excl + cnt;
}

// ---------------------------------------------------------------------------
// K3: fill CSR + per-edge norm + per-node nsum (= sum of norms, for BN-fold)
__global__ void k_fill(const int* __restrict__ src, const int* __restrict__ dst, int E,
                       const float* __restrict__ dinv, int* __restrict__ cursor,
                       int* __restrict__ csr_src, float* __restrict__ csr_norm,
                       float* __restrict__ nsum) {
    int t = blockIdx.x * blockDim.x + threadIdx.x;
    int s, d;
    if (t < E) { s = src[t]; d = dst[t]; }
    else if (t < E + Nn) { s = d = t - E; }
    else return;
    int pos = atomicAdd(&cursor[d], 1);
    const float nm = dinv[s] * dinv[d];
    csr_src[pos]  = s;
    csr_norm[pos] = nm;
    atomicAdd(&nsum[d], nm);
}

// ---------------------------------------------------------------------------
// K4: convert x [B][N][64] fp32 -> xb [N][B][64] bf16 (node-major interleave)
__global__ void k_cvt(const float* __restrict__ x, unsigned* __restrict__ xb) {
    const int t = blockIdx.x * 256 + threadIdx.x;   // enumerates B*N*32 uint outputs
    if (t >= Bb * Nn * 32) return;
    const int c2 = t & 31;
    const int bn = t >> 5;
    const int n  = bn % Nn;
    const int b  = bn / Nn;
    const float2 v = *(const float2*)&x[(size_t)t * 2];
    xb[((size_t)n * Bb + b) * 32 + c2] = pack2(v.x, v.y);
}

// ---------------------------------------------------------------------------
// K5: weight prep (layer 1), FRAG-LINEAR: flat slot f -> {j=f&7, lane=(f>>3)&63,
// rest=f>>9: ks=rest&1, tt=rest>>1}; element = W[k][col], col=tt*16+(lane&15),
// k=ks*32+(lane>>4)*8+j. A wave's MFMA B-read is then 1KB contiguous.
__global__ void k_wt1(const float* __restrict__ W, unsigned short* __restrict__ WTf) {
    const int f = blockIdx.x * 256 + threadIdx.x;
    if (f >= 128 * Ff) return;
    const int j = f & 7, lane = (f >> 3) & 63, rest = f >> 9;
    const int ks = rest & 1, tt = rest >> 1;
    const int col = tt * 16 + (lane & 15);
    const int k = ks * 32 + ((lane >> 4) << 3) + j;
    WTf[f] = (unsigned short)f2bf(W[(size_t)k * 128 + col]);
}

// ---------------------------------------------------------------------------
// K6: fused BN1-finalize + WT2 fold (frag-linear) + shW2. Every block
// redundantly reduces 64-slot stats; blocks 0..63 write WT2f, block 64 shW2.
__global__ __launch_bounds__(128) void k_prep2(const float* __restrict__ gsum,
                                               const float* __restrict__ gsq,
                                               const float* __restrict__ gamma,
                                               const float* __restrict__ beta,
                                               const float* __restrict__ W2,
                                               unsigned short* __restrict__ WT2f,
                                               float* __restrict__ shW2) {
    __shared__ float sc_s[128], sh_s[128];
    const int c = threadIdx.x;
    float s = 0.f, q = 0.f;
    for (int j = 0; j < NSLOTS; ++j) { s += gsum[j * 128 + c]; q += gsq[j * 128 + c]; }
    const float inv = 1.0f / (float)(Bb * Nn);
    const float mu  = s * inv;
    const float var = q * inv - mu * mu;
    const float sc  = gamma[c] * rsqrtf(var + BN_EPS);
    sc_s[c] = sc;
    sh_s[c] = beta[c] - mu * sc;
    __syncthreads();
    if (blockIdx.x < 64) {
#pragma unroll
        for (int i = 0; i < 2; ++i) {
            const int f = blockIdx.x * 256 + i * 128 + c;
            const int j = f & 7, lane = (f >> 3) & 63, rest = f >> 9;  // 0..31
            const int ks = rest & 3, tt = rest >> 2;
            const int col = tt * 16 + (lane & 15);
            const int k = ks * 32 + ((lane >> 4) << 3) + j;
            WT2f[f] = (unsigned short)f2bf(sc_s[k] * W2[(size_t)k * 128 + col]);
        }
    } else {
        float a = 0.f;
        for (int k = 0; k < 128; ++k) a = fmaf(sh_s[k], W2[(size_t)k * 128 + c], a);
        shW2[c] = a;
    }
}

// ---------------------------------------------------------------------------
// K7: FUSED gather-aggregate + MFMA GEMM, ONE-WAVE-BLOCK version.
// Block = 1 wave (64 thr) = 4 nodes = 16 rows, grid = Nn/4 = 5000 blocks.
// R9 lesson: achieved gather BW ~ resident waves x per-wave MLP; 1250 16-node
// blocks starved wave supply (30% occ). 5000 one-wave blocks backfill like
// agg2 (R6: 3.6 TB/s) while keeping unroll-8 MLP. Zero barriers: the wave
// gathers into its PRIVATE sA (4.4KB), MFMAs its own rows (B-frags direct
// from frag-linear global WTf = L2 broadcast), reduces BN stats via shfl_xor.
template <int K, bool L2E>
__global__ __launch_bounds__(64, 6) void k_fmm(const unsigned* __restrict__ G,
                                               const int* __restrict__ rowptr,
                                               const int* __restrict__ csr_src,
                                               const float* __restrict__ csr_norm,
                                               const unsigned short* __restrict__ WTf,
                                               const float* __restrict__ bias,
                                               const float* __restrict__ nsum,
                                               const float* __restrict__ shW2,
                                               unsigned short* __restrict__ Yout,
                                               float* __restrict__ gsum,
                                               float* __restrict__ gsq) {
    constexpr int NKS = K / 32;
    constexpr int AST = K + 8;
    constexpr int NU = K / 32;        // uints per lane per edge (2 or 4)
    constexpr int ROWU = Bb * K / 2;  // uints per node row (128 or 256)
    __shared__ alignas(16) unsigned short sA[16 * AST];

    const int lane = threadIdx.x;
    const int cg = lane & 15, kg = lane >> 4;
    const int g = blockIdx.x;         // node group: nodes 4g..4g+3
    const int row0 = g * 16;

    // gather 4 nodes into private sA (no cross-wave deps, no barriers)
#pragma unroll
    for (int j = 0; j < 4; ++j) {
        const int v = g * 4 + j;
        const int beg = rowptr[v], end = rowptr[v + 1];
        float a[2 * NU];
#pragma unroll
        for (int c = 0; c < 2 * NU; ++c) a[c] = 0.f;
        int e = beg;
        for (; e + 8 <= end; e += 8) {     // 8 outstanding 1KB gathers
            unsigned u[8][NU];
            int si[8];
#pragma unroll
            for (int q = 0; q < 8; ++q) si[q] = csr_src[e + q];
#pragma unroll
            for (int q = 0; q < 8; ++q)
                ldrow<NU>(u[q], G + (size_t)si[q] * ROWU + lane * NU);
#pragma unroll
            for (int q = 0; q < 8; ++q) acc_row<NU>(a, u[q], csr_norm[e + q]);
        }
        for (; e + 4 <= end; e += 4) {
            unsigned u[4][NU];
            int si[4];
#pragma unroll
            for (int q = 0; q < 4; ++q) si[q] = csr_src[e + q];
#pragma unroll
            for (int q = 0; q < 4; ++q)
                ldrow<NU>(u[q], G + (size_t)si[q] * ROWU + lane * NU);
#pragma unroll
            for (int q = 0; q < 4; ++q) acc_row<NU>(a, u[q], csr_norm[e + q]);
        }
        for (; e < end; ++e) {
            unsigned u[NU];
            ldrow<NU>(u, G + (size_t)csr_src[e] * ROWU + lane * NU);
            acc_row<NU>(a, u, csr_norm[e]);
        }
        const int row = j * 4 + kg;       // node-major row = node*4 + batch
        unsigned p[NU];
#pragma unroll
        for (int c = 0; c < NU; ++c) p[c] = pack2(a[2 * c], a[2 * c + 1]);
        if constexpr (NU == 2) *(uint2*)&sA[row * AST + cg * 4] = *(const uint2*)p;
        else                   *(uint4*)&sA[row * AST + cg * 8] = *(const uint4*)p;
    }
    // same-wave LDS RAW: compiler lgkmcnt handles ordering; no barrier.

    // MFMA: rows 0..15 (rowL = cg), 128 cols; B direct from global WTf
    f32x4 acc[8];
#pragma unroll
    for (int t = 0; t < 8; ++t) acc[t] = (f32x4){0.f, 0.f, 0.f, 0.f};
#pragma unroll
    for (int ks = 0; ks < NKS; ++ks) {
        const bf16x8 av = *(const bf16x8*)&sA[cg * AST + ks * 32 + kg * 8];
#pragma unroll
        for (int t = 0; t < 8; ++t) {
            const bf16x8 bv = *(const bf16x8*)&WTf[(size_t)((t * NKS + ks) * 64 + lane) * 8];
            acc[t] = __builtin_amdgcn_mfma_f32_16x16x32_bf16(av, bv, acc[t], 0, 0, 0);
        }
    }

    // epilogue: +bias (+ns*shW2 for L2E), ReLU, bf16 store; BN stats via
    // shfl_xor over kg (node axis) then 16 lanes atomicAdd per col-tile.
    const int rbase = kg * 4;             // 4 regs = 4 batches of node (g*4+kg)
    float ns = 0.f;
    if (L2E) ns = nsum[g * 4 + kg];
    float* gs = gsum + (size_t)(g & (NSLOTS - 1)) * 128;
    float* gq = gsq  + (size_t)(g & (NSLOTS - 1)) * 128;
#pragma unroll
    for (int t = 0; t < 8; ++t) {
        const int col = t * 16 + cg;
        float badd = bias[col];
        if (L2E) badd = fmaf(ns, shW2[col], badd);
        float s = 0.f, q = 0.f;
#pragma unroll
        for (int jj = 0; jj < 4; ++jj) {
            const float y = fmaxf(acc[t][jj] + badd, 0.f);
            Yout[(size_t)(row0 + rbase + jj) * 128 + col] = (unsigned short)f2bf(y);
            s += y; q = fmaf(y, y, q);
        }
        s += __shfl_xor(s, 16); s += __shfl_xor(s, 32);   // sum over kg
        q += __shfl_xor(q, 16); q += __shfl_xor(q, 32);
        if (kg == 0) { atomicAdd(&gs[col], s); atomicAdd(&gq[col], q); }
    }
}

// ---------------------------------------------------------------------------
// K8: BN2 finalize folded into classifier weights:
//   wcs[c] = sc2[c]*Wc[c],  kc = sum_c sh2[c]*Wc[c] + bc
__global__ void k_bnfin2(const float* __restrict__ gsum, const float* __restrict__ gsq,
                         const float* __restrict__ gamma, const float* __restrict__ beta,
                         const float* __restrict__ Wc, const float* __restrict__ bc,
                         float* __restrict__ wcs, float* __restrict__ kc) {
    __shared__ float red[128];
    const int c = threadIdx.x;
    float s = 0.f, q = 0.f;
    for (int j = 0; j < NSLOTS; ++j) { s += gsum[j * 128 + c]; q += gsq[j * 128 + c]; }
    const float inv = 1.0f / (float)(Bb * Nn);
    const float mu  = s * inv;
    const float var = q * inv - mu * mu;
    const float sc  = gamma[c] * rsqrtf(var + BN_EPS);
    const float sh  = beta[c] - mu * sc;
    const float w   = Wc[c];
    wcs[c] = sc * w;
    red[c] = sh * w;
    __syncthreads();
    for (int st = 64; st; st >>= 1) {
        if (c < st) red[c] += red[c + st];
        __syncthreads();
    }
    if (c == 0) kc[0] = red[0] + bc[0];
}

// ---------------------------------------------------------------------------
// K9: classifier on bf16 h2: out[b*Nn+n] = sum_c h2[r][c]*wcs[c] + kc
__global__ __launch_bounds__(256) void k_cls(const unsigned* __restrict__ h2,
                                             const float* __restrict__ wcs,
                                             const float* __restrict__ kc,
                                             float* __restrict__ out) {
    const int wave = threadIdx.x >> 6;
    const int lane = threadIdx.x & 63;
    const size_t row = (size_t)blockIdx.x * 4 + wave;
    if (row >= (size_t)Bb * Nn) return;
    const unsigned w = h2[row * 64 + lane];          // 2 channels
    const float2 wc = *(const float2*)&wcs[lane * 2];
    float p = bf_lo(w) * wc.x + bf_hi(w) * wc.y;
#pragma unroll
    for (int off = 32; off; off >>= 1) p += __shfl_down(p, off);
    if (lane == 0) {
        const int n = (int)(row >> 2), b = (int)(row & 3);
        out[(size_t)b * Nn + n] = p + kc[0];
    }
}

// ---------------------------------------------------------------------------
extern "C" void kernel_launch(void* const* d_in, const int* in_sizes, int n_in,
                              void* d_out, int out_size, void* d_ws, size_t ws_size,
                              hipStream_t stream) {
    const float* x      = (const float*)d_in[0];
    const int*   ei     = (const int*)d_in[1];
    const float* W1     = (const float*)d_in[2];
    const float* b1     = (const float*)d_in[3];
    const float* W2     = (const float*)d_in[4];
    const float* b2     = (const float*)d_in[5];
    const float* gamma1 = (const float*)d_in[6];
    const float* beta1  = (const float*)d_in[7];
    const float* gamma2 = (const float*)d_in[8];
    const float* beta2  = (const float*)d_in[9];
    const float* Wc     = (const float*)d_in[10];
    const float* bc     = (const float*)d_in[11];
    float* out = (float*)d_out;

    const int E = in_sizes[1] / 2;
    const int* src = ei;
    const int* dst = ei + E;

    char* ws = (char*)d_ws;
    size_t off = 0;
    auto alloc = [&](size_t bytes) -> char* {
        char* p = ws + off;
        off += (bytes + 255) & ~(size_t)255;
        return p;
    };
    // zero-init region: deg, nsum, gstat contiguous -> ONE memset
    int*      deg      = (int*)     alloc((size_t)Nn * 4);
    float*    nsum     = (float*)   alloc((size_t)Nn * 4);
    float*    gstat    = (float*)   alloc((size_t)4 * NSLOTS * 128 * 4);
    const size_t zspan = (size_t)((char*)(gstat + 4 * NSLOTS * 128) - (char*)deg);
    float* gsum1 = gstat;
    float* gsq1  = gstat + NSLOTS * 128;
    float* gsum2 = gstat + 2 * NSLOTS * 128;
    float* gsq2  = gstat + 3 * NSLOTS * 128;

    int*      cursor   = (int*)     alloc((size_t)Nn * 4);
    int*      rowptr   = (int*)     alloc((size_t)(Nn + 1) * 4);
    int*      bsum     = (int*)     alloc((size_t)NB * 4);
    float*    dinv     = (float*)   alloc((size_t)Nn * 4);
    int*      csr_src  = (int*)     alloc((size_t)(E + Nn) * 4);
    float*    csr_norm = (float*)   alloc((size_t)(E + Nn) * 4);
    float*    wcs      = (float*)   alloc(128 * 4);
    float*    kc       = (float*)   alloc(256);
    unsigned short* WT1f = (unsigned short*)alloc((size_t)128 * Ff * 2);
    unsigned short* WT2f = (unsigned short*)alloc((size_t)128 * Hh * 2);
    float*          shW2 = (float*)         alloc((size_t)128 * 4);
    unsigned*       xb   = (unsigned*)      alloc((size_t)Nn * Bb * 32 * 4);  // bf16 x node-major
    unsigned short* h1b  = (unsigned short*)alloc((size_t)Bb * Nn * Hh * 2);  // bf16 [80000][128]
    unsigned short* h2b  = (unsigned short*)alloc((size_t)Bb * Nn * Hh * 2);  // bf16 [80000][128]

    (void)hipMemsetAsync(deg, 0, zspan, stream);

    k_deg<<<(E + 255) / 256, 256, 0, stream>>>(dst, E, deg);
    k_scan1<<<NB, 1024, 0, stream>>>(deg, rowptr, bsum);
    k_scan2<<<1, 64, 0, stream>>>(bsum);
    k_scan3<<<NB, 1024, 0, stream>>>(deg, rowptr, bsum, cursor, dinv);
    k_fill<<<(E + Nn + 255) / 256, 256, 0, stream>>>(src, dst, E, dinv, cursor,
                                                     csr_src, csr_norm, nsum);
    k_cvt<<<(Bb * Nn * 32 + 255) / 256, 256, 0, stream>>>(x, xb);
    k_wt1<<<(128 * Ff) / 256, 256, 0, stream>>>(W1, WT1f);

    // Layer 1: fused agg(x)@W1 (+b1, ReLU, BN1 stats, bf16 out)
    k_fmm<Ff, false><<<Nn / 4, 64, 0, stream>>>(
        xb, rowptr, csr_src, csr_norm, WT1f, b1, nullptr, nullptr, h1b, gsum1, gsq1);
    // BN1 finalize + fold into WT2f/shW2
    k_prep2<<<65, 128, 0, stream>>>(gsum1, gsq1, gamma1, beta1, W2, WT2f, shW2);
    // Layer 2: fused agg(h1)@(sc1.W2) + nsum*(sh1@W2) + b2, ReLU, BN2 stats
    k_fmm<Hh, true><<<Nn / 4, 64, 0, stream>>>(
        (const unsigned*)h1b, rowptr, csr_src, csr_norm, WT2f, b2, nsum, shW2,
        h2b, gsum2, gsq2);
    k_bnfin2<<<1, Hh, 0, stream>>>(gsum2, gsq2, gamma2, beta2, Wc, bc, wcs, kc);

    // Classifier (BN2 folded into wcs/kc)
    k_cls<<<(Bb * Nn + 3) / 4, 256, 0, stream>>>((const unsigned*)h2b, wcs, kc, out);
}